// Round 6
// baseline (183.418 us; speedup 1.0000x reference)
//
#include <hip/hip_runtime.h>
#include <stdint.h>

// SelfAttentionBlock: B=4, C=256, H=W=64 (N=4096), CQK=32.
//   cvt : W fp32->f16 (Wh) + x -> f16 transposed xh[b][n][c]
//   proj: register MFMA GEMM -> Qt[n][32]*log2e, Kt[n][32], V[c][n] (f16)
//   attn: flash attention, 1024 threads = 4 j-split groups x 4 waves (4 waves/SIMD).
//         V read directly from global (L2-resident) as B-fragments - no LDS staging,
//         no vmcnt drains. K global->reg. Swapped QK^T, lane-owns-row softmax,
//         defer-max, log2 domain. P double-buffered in LDS (1 barrier/chunk).
//         4-way flash-combine in epilogue through LDS Ocomb (aliases P bufs).

#define NB 4
#define CD 256
#define ND 4096
#define CQ 32
#define LOG2E 1.4426950408889634f

typedef __attribute__((ext_vector_type(4))) float f32x4;
typedef __attribute__((ext_vector_type(8))) _Float16 f16x8;
typedef __attribute__((ext_vector_type(4))) unsigned short u16x4;
typedef __attribute__((ext_vector_type(8))) unsigned short u16x8;
typedef __attribute__((ext_vector_type(2))) unsigned int u32x2;
typedef __attribute__((ext_vector_type(4))) int i32x4;

static __device__ __forceinline__ unsigned short f2h(float f) {
    union { _Float16 h; unsigned short u; } cv; cv.h = (_Float16)f; return cv.u;
}
static __device__ __forceinline__ float fexp2(float xv) {
    float r; asm("v_exp_f32 %0, %1" : "=v"(r) : "v"(xv)); return r;
}

#define BARRIER() asm volatile("s_waitcnt lgkmcnt(0)\n\ts_barrier" ::: "memory")

// ---------------- fused cvt: W fp32->f16 and x -> xh[b][n][c] f16 ----------------
__global__ __launch_bounds__(256) void cvt_kernel(
    const float* __restrict__ x,
    const float* __restrict__ wq, const float* __restrict__ wk,
    const float* __restrict__ wv,
    unsigned short* __restrict__ xh, unsigned short* __restrict__ Wh)
{
    __shared__ unsigned short xt[64 * 72];
    if (blockIdx.x >= 1024) {   // wcvt (80 blocks)
        const int idx = (blockIdx.x - 1024) * 256 + threadIdx.x;
        const int m = idx >> 6, kq = (idx & 63) << 2;
        const float* src = (m < 32) ? (wq + (size_t)m * CD + kq)
                         : (m < 64) ? (wk + (size_t)(m - 32) * CD + kq)
                                    : (wv + (size_t)(m - 64) * CD + kq);
        const f32x4 v = *reinterpret_cast<const f32x4*>(src);
        u16x4 h;
#pragma unroll
        for (int u = 0; u < 4; ++u) h[u] = f2h(v[u]);
        *reinterpret_cast<u16x4*>(Wh + (size_t)m * CD + kq) = h;
        return;
    }
    const int t  = threadIdx.x;
    const int nt = blockIdx.x & 63, ct = (blockIdx.x >> 6) & 3, b = blockIdx.x >> 8;
    const int n0 = nt << 6, c0 = ct << 6;

    const float* xb = x + ((size_t)(b * CD + c0)) * ND + n0;
#pragma unroll
    for (int s = t; s < 1024; s += 256) {
        const int c = s >> 4, nq = (s & 15) << 2;
        const f32x4 v = *reinterpret_cast<const f32x4*>(xb + (size_t)c * ND + nq);
        u16x4 h;
#pragma unroll
        for (int u = 0; u < 4; ++u) h[u] = f2h(v[u]);
        *reinterpret_cast<u16x4*>(&xt[c * 72 + nq]) = h;
    }
    __syncthreads();

    const int n = t >> 2, cb = (t & 3) << 4;
    u16x8 o0, o1;
#pragma unroll
    for (int u = 0; u < 8; ++u) o0[u] = xt[(cb + u) * 72 + n];
#pragma unroll
    for (int u = 0; u < 8; ++u) o1[u] = xt[(cb + 8 + u) * 72 + n];
    unsigned short* dst = xh + ((size_t)(b * ND + n0 + n)) * CD + c0 + cb;
    *reinterpret_cast<u16x8*>(dst)     = o0;
    *reinterpret_cast<u16x8*>(dst + 8) = o1;
}

// ---------------- projection: register MFMA GEMM ----------------
__global__ __launch_bounds__(320) void proj_kernel(
    const unsigned short* __restrict__ Wh, const unsigned short* __restrict__ xh,
    const float* __restrict__ bq, const float* __restrict__ bk,
    const float* __restrict__ bv,
    unsigned short* __restrict__ Qt, unsigned short* __restrict__ Kt,
    unsigned short* __restrict__ V)
{
    const int tid = threadIdx.x;
    const int lane = tid & 63;
    const int w = __builtin_amdgcn_readfirstlane(tid >> 6);
    const int m16 = lane & 15, g4 = lane >> 4;
    const int b = blockIdx.x >> 6, n0 = (blockIdx.x & 63) << 6;

    f32x4 acc[4][4];
#pragma unroll
    for (int a = 0; a < 4; ++a)
#pragma unroll
        for (int c = 0; c < 4; ++c) acc[a][c] = (f32x4){0.f, 0.f, 0.f, 0.f};

    const unsigned short* Wrow = Wh + (size_t)(w * 64 + m16) * CD;
    const unsigned short* Xrow = xh + ((size_t)(b * ND + n0 + m16)) * CD;

#pragma unroll
    for (int ks = 0; ks < 8; ++ks) {
        const int ko = ks * 32 + g4 * 8;
        f16x8 af[4], bf[4];
#pragma unroll
        for (int ms = 0; ms < 4; ++ms)
            af[ms] = *reinterpret_cast<const f16x8*>(Wrow + (size_t)ms * 16 * CD + ko);
#pragma unroll
        for (int ns = 0; ns < 4; ++ns)
            bf[ns] = *reinterpret_cast<const f16x8*>(Xrow + (size_t)ns * 16 * CD + ko);
#pragma unroll
        for (int ms = 0; ms < 4; ++ms)
#pragma unroll
            for (int ns = 0; ns < 4; ++ns)
                acc[ms][ns] = __builtin_amdgcn_mfma_f32_16x16x32_f16(
                    af[ms], bf[ns], acc[ms][ns], 0, 0, 0);
    }

#pragma unroll
    for (int ms = 0; ms < 4; ++ms) {
        const int seg = w * 64 + ms * 16;
        const int mb  = seg + g4 * 4;
        f32x4 bias;
        if (seg < 32)       bias = *reinterpret_cast<const f32x4*>(bq + mb);
        else if (seg < 64)  bias = *reinterpret_cast<const f32x4*>(bk + mb - 32);
        else                bias = *reinterpret_cast<const f32x4*>(bv + mb - 64);
#pragma unroll
        for (int ns = 0; ns < 4; ++ns) {
            const int n = n0 + ns * 16 + m16;
            u16x4 h;
            if (seg < 32) {
#pragma unroll
                for (int r = 0; r < 4; ++r)
                    h[r] = f2h(fmaxf(acc[ms][ns][r] + bias[r], 0.f) * LOG2E);
                *reinterpret_cast<u16x4*>(Qt + ((size_t)(b * ND + n)) * CQ + mb) = h;
            } else if (seg < 64) {
#pragma unroll
                for (int r = 0; r < 4; ++r) h[r] = f2h(fmaxf(acc[ms][ns][r] + bias[r], 0.f));
                *reinterpret_cast<u16x4*>(Kt + ((size_t)(b * ND + n)) * CQ + (mb - 32)) = h;
            } else {
#pragma unroll
                for (int r = 0; r < 4; ++r)
                    V[((size_t)(b * CD + (mb - 64 + r))) * ND + n] =
                        f2h(fmaxf(acc[ms][ns][r] + bias[r], 0.f));
            }
        }
    }
}

// ---------------- flash attention: 4 j-split groups, 16 waves ----------------
// grid: NB*64 blocks (b, 64-row i-strip), 1024 threads.
// Group g (waves 4g..4g+3) handles j-chunks k*256 + g*64, k=0..15.
// Per chunk: QK^T swapped (K in regs from global), in-lane softmax, P->LDS
// (double-buffered), ONE barrier, PV with V B-frags direct from global (L2).
__global__ __launch_bounds__(1024, 4) void attn_kernel(
    const unsigned short* __restrict__ Qt, const unsigned short* __restrict__ Kt,
    const unsigned short* __restrict__ V, const float* __restrict__ x,
    const float* __restrict__ gamma, float* __restrict__ out)
{
    // LDS: loop phase = pbuf[4][2][8192] | scales[4][2][64]f32 | flags[4][2][4]i32
    //      epilogue  = Ocomb[64][260]f32 (aliases pbuf/scales/flags) + mfin/lfin/ffac
    __shared__ __align__(16) unsigned char smem[70784];
    unsigned char* pbase = smem;                       // 65536
    float* scales = reinterpret_cast<float*>(smem + 65536);  // 2048
    int*   flags  = reinterpret_cast<int*>(smem + 67584);    // 128
    float* Ocomb  = reinterpret_cast<float*>(smem);          // 64*260*4 = 66560 (alias)
    float* mfin   = reinterpret_cast<float*>(smem + 67712);  // [4][64]
    float* lfin   = reinterpret_cast<float*>(smem + 68736);  // [4][64]
    float* ffac   = reinterpret_cast<float*>(smem + 69760);  // [4][64]

    const int tid  = threadIdx.x;
    const int lane = tid & 63;
    const int w16  = __builtin_amdgcn_readfirstlane(tid >> 6);
    const int g    = w16 >> 2;      // j-group 0..3
    const int ws   = w16 & 3;       // i-strip (QK) / c-slice (PV)
    const int m16  = lane & 15;
    const int g4   = lane >> 4;
    const int wg   = (blockIdx.x & 7) * 32 + (blockIdx.x >> 3);  // XCD swizzle
    const int b    = wg >> 6;
    const int i0   = (wg & 63) << 6;

    // Q as B-operand (col=i=m16, k=g4*8+u)
    const f16x8 qfrag = *reinterpret_cast<const f16x8*>(
        Qt + ((size_t)(b * ND + i0 + ws * 16 + m16)) * CQ + g4 * 8);
    // K as A-operand from global (row j=m16 within tile, k=g4*8+u)
    const unsigned short* kbase = Kt + ((size_t)(b * ND + m16)) * CQ + g4 * 8;
    // V B-frag pointers per c-subtile (col c=m16, k=j=g4*8+u)
    const unsigned short* vp[4];
#pragma unroll
    for (int cs = 0; cs < 4; ++cs)
        vp[cs] = V + ((size_t)(b * CD + ws * 64 + cs * 16 + m16)) * ND + g4 * 8;

    f32x4 oacc[4][4];
#pragma unroll
    for (int a = 0; a < 4; ++a)
#pragma unroll
        for (int c = 0; c < 4; ++c) oacc[a][c] = (f32x4){0.f, 0.f, 0.f, 0.f};
    float mrow = -1e30f, lrow = 0.f;
    const f32x4 zero4 = {0.f, 0.f, 0.f, 0.f};

    const int pg   = g * 16384;          // group P region base (bytes)
    const int irow = ws * 16 + m16;      // softmax row this lane owns
    const int iswz = (m16 & 7) << 4;     // XOR swizzle (row-dependent bits)

    f16x8 kreg[4];
#pragma unroll
    for (int t = 0; t < 4; ++t)
        kreg[t] = *reinterpret_cast<const f16x8*>(kbase + (size_t)(g * 64 + t * 16) * CQ);

#pragma unroll 1
    for (int k = 0; k < 16; ++k) {
        const int j0 = k * 256 + g * 64;
        const int par = k & 1;
        const int pbuf = pg + par * 8192;

        // ---- QK^T swapped: D[j][i], lane owns column i=irow, 16 j-values ----
        f32x4 s[4];
#pragma unroll
        for (int t = 0; t < 4; ++t)
            s[t] = __builtin_amdgcn_mfma_f32_16x16x32_f16(kreg[t], qfrag, zero4, 0, 0, 0);
        if (k < 15) {
#pragma unroll
            for (int t = 0; t < 4; ++t)
                kreg[t] = *reinterpret_cast<const f16x8*>(
                    kbase + (size_t)(j0 + 256 + t * 16) * CQ);
        }

        // ---- softmax (log2 domain, defer-max) ----
        float pm = s[0][0];
#pragma unroll
        for (int t = 0; t < 4; ++t)
#pragma unroll
            for (int r = 0; r < 4; ++r) pm = fmaxf(pm, s[t][r]);
        pm = fmaxf(pm, __shfl_xor(pm, 16));
        pm = fmaxf(pm, __shfl_xor(pm, 32));
        float sc = 1.0f;
        int myresc = 0;
        if (__ballot(pm <= mrow + 8.0f) != ~0ull) {
            const float mnew = fmaxf(mrow, pm);
            sc = fexp2(mrow - mnew);
            mrow = mnew;
            myresc = 1;
        }
        float rs = 0.f;
#pragma unroll
        for (int t = 0; t < 4; ++t)
#pragma unroll
            for (int r = 0; r < 4; ++r) { s[t][r] = fexp2(s[t][r] - mrow); rs += s[t][r]; }
        rs += __shfl_xor(rs, 16);
        rs += __shfl_xor(rs, 32);
        lrow = lrow * sc + rs;

        // ---- P -> LDS (4x ds_write_b64, swizzled) + scale + flag ----
#pragma unroll
        for (int t = 0; t < 4; ++t) {
            u32x2 pw;
            pw[0] = __builtin_bit_cast(unsigned int,
                        __builtin_amdgcn_cvt_pkrtz(s[t][0], s[t][1]));
            pw[1] = __builtin_bit_cast(unsigned int,
                        __builtin_amdgcn_cvt_pkrtz(s[t][2], s[t][3]));
            const int lo = (irow * 128 + t * 32 + g4 * 8) ^ iswz;
            *reinterpret_cast<u32x2*>(pbase + pbuf + lo) = pw;
        }
        if (g4 == 0) scales[(g * 2 + par) * 64 + irow] = sc;
        if (lane == 0) flags[(g * 2 + par) * 4 + ws] = myresc;

        BARRIER();   // lgkm-only: P/scale/flag visible; no vmcnt drain

        // ---- PV: V B-frags from global (L2), P A-frags from LDS ----
        f16x8 vf0[4], vf1[4];
#pragma unroll
        for (int cs = 0; cs < 4; ++cs)
            vf0[cs] = *reinterpret_cast<const f16x8*>(vp[cs] + (size_t)j0);
#pragma unroll
        for (int cs = 0; cs < 4; ++cs)
            vf1[cs] = *reinterpret_cast<const f16x8*>(vp[cs] + (size_t)j0 + 32);

        const i32x4 fl = *reinterpret_cast<const i32x4*>(flags + (g * 2 + par) * 4);
        const int anyresc = __builtin_amdgcn_readfirstlane(fl[0] | fl[1] | fl[2] | fl[3]);
        if (anyresc) {
#pragma unroll
            for (int is = 0; is < 4; ++is) {
                const f32x4 sr = *reinterpret_cast<const f32x4*>(
                    scales + (g * 2 + par) * 64 + is * 16 + g4 * 4);
#pragma unroll
                for (int r = 0; r < 4; ++r)
#pragma unroll
                    for (int cs = 0; cs < 4; ++cs) oacc[is][cs][r] *= sr[r];
            }
        }

        __builtin_amdgcn_s_setprio(1);
#pragma unroll
        for (int is = 0; is < 4; ++is) {
            const int lo = ((is * 16 + m16) * 128 + g4 * 16) ^ iswz;
            const f16x8 pf = *reinterpret_cast<const f16x8*>(pbase + pbuf + lo);
#pragma unroll
            for (int cs = 0; cs < 4; ++cs)
                oacc[is][cs] = __builtin_amdgcn_mfma_f32_16x16x32_f16(
                    pf, vf0[cs], oacc[is][cs], 0, 0, 0);
        }
#pragma unroll
        for (int is = 0; is < 4; ++is) {
            const int lo = ((is * 16 + m16) * 128 + 64 + g4 * 16) ^ iswz;
            const f16x8 pf = *reinterpret_cast<const f16x8*>(pbase + pbuf + lo);
#pragma unroll
            for (int cs = 0; cs < 4; ++cs)
                oacc[is][cs] = __builtin_amdgcn_mfma_f32_16x16x32_f16(
                    pf, vf1[cs], oacc[is][cs], 0, 0, 0);
        }
        __builtin_amdgcn_s_setprio(0);
    }

    // ---- epilogue: 4-way flash combine ----
    if (g4 == 0) { mfin[g * 64 + irow] = mrow; lfin[g * 64 + irow] = lrow; }
    __syncthreads();

    if (tid < 64) {
        const float m0 = mfin[tid], m1 = mfin[64 + tid],
                    m2 = mfin[128 + tid], m3 = mfin[192 + tid];
        const float ms = fmaxf(fmaxf(m0, m1), fmaxf(m2, m3));
        const float e0 = fexp2(m0 - ms), e1 = fexp2(m1 - ms),
                    e2 = fexp2(m2 - ms), e3 = fexp2(m3 - ms);
        const float den = lfin[tid] * e0 + lfin[64 + tid] * e1 +
                          lfin[128 + tid] * e2 + lfin[192 + tid] * e3;
        const float rinv = 1.0f / den;
        ffac[tid]       = e0 * rinv;
        ffac[64 + tid]  = e1 * rinv;
        ffac[128 + tid] = e2 * rinv;
        ffac[192 + tid] = e3 * rinv;
    }
    __syncthreads();   // pbuf dead; Ocomb aliases it from here

#pragma unroll
    for (int gg = 0; gg < 4; ++gg) {
        if (g == gg) {
#pragma unroll
            for (int is = 0; is < 4; ++is) {
                const f32x4 f = *reinterpret_cast<const f32x4*>(
                    ffac + g * 64 + is * 16 + g4 * 4);
#pragma unroll
                for (int cs = 0; cs < 4; ++cs) {
#pragma unroll
                    for (int r = 0; r < 4; ++r) {
                        const int i = is * 16 + g4 * 4 + r;
                        const int c = ws * 64 + cs * 16 + m16;
                        const float val = oacc[is][cs][r] * f[r];
                        if (gg == 0) Ocomb[i * 260 + c] = val;
                        else         Ocomb[i * 260 + c] += val;
                    }
                }
            }
        }
        __syncthreads();
    }

    const float gm = gamma[0];
#pragma unroll
    for (int pass = 0; pass < 4; ++pass) {
        const int c  = (tid >> 4) + pass * 64;
        const int iq = (tid & 15) * 4;
        f32x4 o;
#pragma unroll
        for (int u = 0; u < 4; ++u) o[u] = Ocomb[(iq + u) * 260 + c];
        const size_t idx = ((size_t)(b * CD + c)) * ND + i0 + iq;
        const f32x4 xv = *reinterpret_cast<const f32x4*>(x + idx);
        f32x4 res;
#pragma unroll
        for (int u = 0; u < 4; ++u) res[u] = gm * o[u] + xv[u];
        *reinterpret_cast<f32x4*>(out + idx) = res;
    }
}

extern "C" void kernel_launch(void* const* d_in, const int* in_sizes, int n_in,
                              void* d_out, int out_size, void* d_ws, size_t ws_size,
                              hipStream_t stream) {
    const float* x     = (const float*)d_in[0];
    const float* wq    = (const float*)d_in[1];
    const float* bq    = (const float*)d_in[2];
    const float* wk    = (const float*)d_in[3];
    const float* bk    = (const float*)d_in[4];
    const float* wv    = (const float*)d_in[5];
    const float* bv    = (const float*)d_in[6];
    const float* gamma = (const float*)d_in[7];

    unsigned short* Qt = (unsigned short*)d_ws;               // 1MB (scaled by log2e)
    unsigned short* Kt = Qt + (size_t)NB * ND * CQ;           // 1MB
    unsigned short* V  = Kt + (size_t)NB * ND * CQ;           // 8MB
    unsigned short* Wh = V + (size_t)NB * CD * ND;            // 160KB
    unsigned short* xh = Wh + (size_t)320 * CD;               // 8MB
    float* out = (float*)d_out;

    cvt_kernel<<<dim3(1104),     dim3(256),  0, stream>>>(x, wq, wk, wv, xh, Wh);
    proj_kernel<<<dim3(NB * 64), dim3(320),  0, stream>>>(Wh, xh, bq, bk, bv, Qt, Kt, V);
    attn_kernel<<<dim3(NB * 64), dim3(1024), 0, stream>>>(Qt, Kt, V, x, gamma, out);
}

// Round 7
// 172.311 us; speedup vs baseline: 1.0645x; 1.0645x over previous
//
#include <hip/hip_runtime.h>
#include <stdint.h>

// SelfAttentionBlock: B=4, C=256, H=W=64 (N=4096), CQK=32.
//   cvt : W fp32->f16 (Wh) + x -> f16 transposed xh[b][n][c]
//   proj: register MFMA GEMM -> Qt[n][32]*log2e, Kt[n][32],
//         Vp = V pre-packed in PV B-fragment order [b][jblk][ct][lane][8]
//   attn: ZERO-BARRIER flash attention. 1024 thr = 16 independent waves
//         (jg 0..3 = N/4 j-stripe, cg 0..3 = 64-c slice). Per wave: swapped
//         QK^T (K,Q frags coalesced from global), in-register softmax
//         (defer-max, log2 domain), ds_bpermute P-redistribution (no LDS P),
//         PV with coalesced Vp frags from global/L2. Epilogue: 4-way
//         flash-combine through LDS. QK^T is 4x redundant across cg - the
//         price of total wave independence.

#define NB 4
#define CD 256
#define ND 4096
#define CQ 32
#define LOG2E 1.4426950408889634f

typedef __attribute__((ext_vector_type(4))) float f32x4;
typedef __attribute__((ext_vector_type(8))) _Float16 f16x8;
typedef __attribute__((ext_vector_type(4))) unsigned short u16x4;
typedef __attribute__((ext_vector_type(8))) unsigned short u16x8;
typedef __attribute__((ext_vector_type(4))) unsigned int u32x4;

static __device__ __forceinline__ unsigned short f2h(float f) {
    union { _Float16 h; unsigned short u; } cv; cv.h = (_Float16)f; return cv.u;
}
static __device__ __forceinline__ float fexp2(float xv) {
    float r; asm("v_exp_f32 %0, %1" : "=v"(r) : "v"(xv)); return r;
}
static __device__ __forceinline__ float bpermf(int byteaddr, float v) {
    return __int_as_float(__builtin_amdgcn_ds_bpermute(byteaddr, __float_as_int(v)));
}
static __device__ __forceinline__ unsigned int bpermu(int byteaddr, unsigned int v) {
    return (unsigned int)__builtin_amdgcn_ds_bpermute(byteaddr, (int)v);
}

// ---------------- fused cvt: W fp32->f16 and x -> xh[b][n][c] f16 ----------------
__global__ __launch_bounds__(256) void cvt_kernel(
    const float* __restrict__ x,
    const float* __restrict__ wq, const float* __restrict__ wk,
    const float* __restrict__ wv,
    unsigned short* __restrict__ xh, unsigned short* __restrict__ Wh)
{
    __shared__ unsigned short xt[64 * 72];
    if (blockIdx.x >= 1024) {   // wcvt (80 blocks)
        const int idx = (blockIdx.x - 1024) * 256 + threadIdx.x;
        const int m = idx >> 6, kq = (idx & 63) << 2;
        const float* src = (m < 32) ? (wq + (size_t)m * CD + kq)
                         : (m < 64) ? (wk + (size_t)(m - 32) * CD + kq)
                                    : (wv + (size_t)(m - 64) * CD + kq);
        const f32x4 v = *reinterpret_cast<const f32x4*>(src);
        u16x4 h;
#pragma unroll
        for (int u = 0; u < 4; ++u) h[u] = f2h(v[u]);
        *reinterpret_cast<u16x4*>(Wh + (size_t)m * CD + kq) = h;
        return;
    }
    const int t  = threadIdx.x;
    const int nt = blockIdx.x & 63, ct = (blockIdx.x >> 6) & 3, b = blockIdx.x >> 8;
    const int n0 = nt << 6, c0 = ct << 6;

    const float* xb = x + ((size_t)(b * CD + c0)) * ND + n0;
#pragma unroll
    for (int s = t; s < 1024; s += 256) {
        const int c = s >> 4, nq = (s & 15) << 2;
        const f32x4 v = *reinterpret_cast<const f32x4*>(xb + (size_t)c * ND + nq);
        u16x4 h;
#pragma unroll
        for (int u = 0; u < 4; ++u) h[u] = f2h(v[u]);
        *reinterpret_cast<u16x4*>(&xt[c * 72 + nq]) = h;
    }
    __syncthreads();

    const int n = t >> 2, cb = (t & 3) << 4;
    u16x8 o0, o1;
#pragma unroll
    for (int u = 0; u < 8; ++u) o0[u] = xt[(cb + u) * 72 + n];
#pragma unroll
    for (int u = 0; u < 8; ++u) o1[u] = xt[(cb + 8 + u) * 72 + n];
    unsigned short* dst = xh + ((size_t)(b * ND + n0 + n)) * CD + c0 + cb;
    *reinterpret_cast<u16x8*>(dst)     = o0;
    *reinterpret_cast<u16x8*>(dst + 8) = o1;
}

// ---------------- projection: register MFMA GEMM ----------------
// wave 0: Q,K rows (D[c][n] orientation); waves 1-4: V rows with SWAPPED
// operands (D[n][c]) so each lane's 4 acc values are consecutive n -> one
// u16x4 store into the Vp packed-fragment layout.
__global__ __launch_bounds__(320) void proj_kernel(
    const unsigned short* __restrict__ Wh, const unsigned short* __restrict__ xh,
    const float* __restrict__ bq, const float* __restrict__ bk,
    const float* __restrict__ bv,
    unsigned short* __restrict__ Qt, unsigned short* __restrict__ Kt,
    unsigned short* __restrict__ Vp)
{
    const int tid = threadIdx.x;
    const int lane = tid & 63;
    const int w = __builtin_amdgcn_readfirstlane(tid >> 6);
    const int m16 = lane & 15, g4 = lane >> 4;
    const int b = blockIdx.x >> 6, n0 = (blockIdx.x & 63) << 6;

    f32x4 acc[4][4];
#pragma unroll
    for (int a = 0; a < 4; ++a)
#pragma unroll
        for (int c = 0; c < 4; ++c) acc[a][c] = (f32x4){0.f, 0.f, 0.f, 0.f};

    const unsigned short* Wrow = Wh + (size_t)(w * 64 + m16) * CD;
    const unsigned short* Xrow = xh + ((size_t)(b * ND + n0 + m16)) * CD;

#pragma unroll
    for (int ks = 0; ks < 8; ++ks) {
        const int ko = ks * 32 + g4 * 8;
        f16x8 af[4], bf[4];
#pragma unroll
        for (int ms = 0; ms < 4; ++ms)
            af[ms] = *reinterpret_cast<const f16x8*>(Wrow + (size_t)ms * 16 * CD + ko);
#pragma unroll
        for (int ns = 0; ns < 4; ++ns)
            bf[ns] = *reinterpret_cast<const f16x8*>(Xrow + (size_t)ns * 16 * CD + ko);
        if (w == 0) {
#pragma unroll
            for (int ms = 0; ms < 4; ++ms)
#pragma unroll
                for (int ns = 0; ns < 4; ++ns)
                    acc[ms][ns] = __builtin_amdgcn_mfma_f32_16x16x32_f16(
                        af[ms], bf[ns], acc[ms][ns], 0, 0, 0);
        } else {
#pragma unroll
            for (int ms = 0; ms < 4; ++ms)
#pragma unroll
                for (int ns = 0; ns < 4; ++ns)
                    acc[ms][ns] = __builtin_amdgcn_mfma_f32_16x16x32_f16(
                        bf[ns], af[ms], acc[ms][ns], 0, 0, 0);
        }
    }

    if (w == 0) {   // Q (ms 0,1) + K (ms 2,3): D[c-row][n-col], col = m16 = n
#pragma unroll
        for (int ms = 0; ms < 4; ++ms) {
            const int seg = ms * 16;
            const int mb  = seg + g4 * 4;
            const f32x4 bias = (seg < 32) ? *reinterpret_cast<const f32x4*>(bq + mb)
                                          : *reinterpret_cast<const f32x4*>(bk + (mb - 32));
#pragma unroll
            for (int ns = 0; ns < 4; ++ns) {
                const int n = n0 + ns * 16 + m16;
                u16x4 h;
                if (seg < 32) {
#pragma unroll
                    for (int r = 0; r < 4; ++r)
                        h[r] = f2h(fmaxf(acc[ms][ns][r] + bias[r], 0.f) * LOG2E);
                    *reinterpret_cast<u16x4*>(Qt + ((size_t)(b * ND + n)) * CQ + mb) = h;
                } else {
#pragma unroll
                    for (int r = 0; r < 4; ++r)
                        h[r] = f2h(fmaxf(acc[ms][ns][r] + bias[r], 0.f));
                    *reinterpret_cast<u16x4*>(Kt + ((size_t)(b * ND + n)) * CQ + (mb - 32)) = h;
                }
            }
        }
    } else {        // V: D[n-row][c-col], col = m16 = c; rows = n = g4*4+r
        const int cbase = (w - 1) * 64;
#pragma unroll
        for (int ms = 0; ms < 4; ++ms) {
            const int c = cbase + ms * 16 + m16;
            const float bval = bv[c];
#pragma unroll
            for (int ns = 0; ns < 4; ++ns) {
                const int n = n0 + ns * 16 + g4 * 4;
                u16x4 h;
#pragma unroll
                for (int r = 0; r < 4; ++r)
                    h[r] = f2h(fmaxf(acc[ms][ns][r] + bval, 0.f));
                // Vp[b][jblk=n>>5][ct=c>>4][lane' = ((n>>3)&3)*16 + (c&15)][u = n&7]
                unsigned short* dst = Vp
                    + ((size_t)((b * 128 + (n >> 5)) * 16 + (c >> 4))) * 512
                    + ((((n >> 3) & 3) * 16 + (c & 15)) * 8) + (n & 7);
                *reinterpret_cast<u16x4*>(dst) = h;
            }
        }
    }
}

// ---------------- flash attention: zero-barrier, 16 independent waves ----------------
// grid: NB*128 blocks (b, 32-row i-strip), 1024 threads.
// wave (jg,cg): 32 i x [jg*1024, +1024) j x [cg*64, +64) c. No LDS/barriers
// in the loop; flash-combine over jg in the epilogue.
__global__ __launch_bounds__(1024) void attn_kernel(
    const unsigned short* __restrict__ Qt, const unsigned short* __restrict__ Kt,
    const unsigned short* __restrict__ Vp, const float* __restrict__ x,
    const float* __restrict__ gamma, float* __restrict__ out)
{
    __shared__ float Ocomb[4][32][261];   // 133632 B, epilogue only
    __shared__ float mfin[128], lfin[128];

    const int tid  = threadIdx.x;
    const int lane = tid & 63;
    const int w16  = __builtin_amdgcn_readfirstlane(tid >> 6);
    const int jg   = w16 >> 2, cg = w16 & 3;
    const int m16  = lane & 15, g4 = lane >> 4;
    const int wg   = (blockIdx.x & 7) * 64 + (blockIdx.x >> 3);  // XCD swizzle (512/8)
    const int b    = wg >> 7;
    const int i0   = (wg & 127) << 5;

    // Q as B-operand: col=i=m16, k=g4*8+u  (2 i-tiles)
    f16x8 qf[2];
#pragma unroll
    for (int it = 0; it < 2; ++it)
        qf[it] = *reinterpret_cast<const f16x8*>(
            Qt + ((size_t)(b * ND + i0 + it * 16 + m16)) * CQ + g4 * 8);

    const unsigned short* kb  = Kt + ((size_t)(b * ND + m16)) * CQ + g4 * 8;
    const unsigned short* vpb = Vp + ((size_t)(b * 128 * 16 + cg * 4)) * 512 + lane * 8;

    f32x4 oacc[2][4];
#pragma unroll
    for (int a = 0; a < 2; ++a)
#pragma unroll
        for (int c = 0; c < 4; ++c) oacc[a][c] = (f32x4){0.f, 0.f, 0.f, 0.f};
    float mrow[2] = {-1e30f, -1e30f}, lrow[2] = {0.f, 0.f};
    const f32x4 zero4 = {0.f, 0.f, 0.f, 0.f};

    // bpermute source-lane byte addrs for P redistribution
    const int aA = (m16 + ((lane & 16) << 1)) << 2;   // lane m16 + (g4&1)*32
    const int aB = aA + 64;                           // +16 lanes

#pragma unroll 1
    for (int ch = 0; ch < 16; ++ch) {
        const int j0 = jg * 1024 + ch * 64;

        // K A-frags: row=j=m16(+jt*16), k=g4*8+u — 16B/lane coalesced
        f16x8 kf[4];
#pragma unroll
        for (int jt = 0; jt < 4; ++jt)
            kf[jt] = *reinterpret_cast<const f16x8*>(kb + (size_t)(j0 + jt * 16) * CQ);

        // swapped QK^T: D[j][i], col=i=m16, row j = jt*16 + g4*4 + r
        f32x4 s[2][4];
#pragma unroll
        for (int it = 0; it < 2; ++it)
#pragma unroll
            for (int jt = 0; jt < 4; ++jt)
                s[it][jt] = __builtin_amdgcn_mfma_f32_16x16x32_f16(
                    kf[jt], qf[it], zero4, 0, 0, 0);

        // V B-frags (coalesced packed layout) — issue early, consumed in PV
        const int jblk0 = j0 >> 5;
        f16x8 vf[2][4];
#pragma unroll
        for (int jb = 0; jb < 2; ++jb)
#pragma unroll
            for (int ct = 0; ct < 4; ++ct)
                vf[jb][ct] = *reinterpret_cast<const f16x8*>(
                    vpb + (size_t)((jblk0 + jb) * 16 + ct) * 512);

        // ---- softmax (log2 domain, defer-max); lane owns rows it*16+m16 ----
        float pm[2];
#pragma unroll
        for (int it = 0; it < 2; ++it) {
            float v = s[it][0][0];
#pragma unroll
            for (int jt = 0; jt < 4; ++jt)
#pragma unroll
                for (int r = 0; r < 4; ++r) v = fmaxf(v, s[it][jt][r]);
            v = fmaxf(v, __shfl_xor(v, 16));
            v = fmaxf(v, __shfl_xor(v, 32));
            pm[it] = v;
        }
        const bool ok = (pm[0] <= mrow[0] + 8.0f) && (pm[1] <= mrow[1] + 8.0f);
        if (__ballot(ok) != ~0ull) {
#pragma unroll
            for (int it = 0; it < 2; ++it) {
                const float mn = fmaxf(mrow[it], pm[it]);
                const float sc = fexp2(mrow[it] - mn);
                mrow[it] = mn;
                lrow[it] *= sc;
                // oacc rows are i=it*16+g4*4+r; fetch owner lane's sc
#pragma unroll
                for (int r = 0; r < 4; ++r) {
                    const float s2 = bpermf((g4 * 4 + r) << 2, sc);
#pragma unroll
                    for (int ct = 0; ct < 4; ++ct) oacc[it][ct][r] *= s2;
                }
            }
        }
#pragma unroll
        for (int it = 0; it < 2; ++it) {
            float rs = 0.f;
#pragma unroll
            for (int jt = 0; jt < 4; ++jt)
#pragma unroll
                for (int r = 0; r < 4; ++r) {
                    s[it][jt][r] = fexp2(s[it][jt][r] - mrow[it]);
                    rs += s[it][jt][r];
                }
            rs += __shfl_xor(rs, 16);
            rs += __shfl_xor(rs, 32);
            lrow[it] += rs;
        }

        // ---- P: cvt to f16 pairs, then bpermute into PV A-frag layout ----
        unsigned int c16[2][4][2];
#pragma unroll
        for (int it = 0; it < 2; ++it)
#pragma unroll
            for (int jt = 0; jt < 4; ++jt) {
                c16[it][jt][0] = __builtin_bit_cast(unsigned int,
                    __builtin_amdgcn_cvt_pkrtz(s[it][jt][0], s[it][jt][1]));
                c16[it][jt][1] = __builtin_bit_cast(unsigned int,
                    __builtin_amdgcn_cvt_pkrtz(s[it][jt][2], s[it][jt][3]));
            }
        const bool hi = (lane & 32) != 0;   // jt-select = g4>>1
        f16x8 pa[2][2];
#pragma unroll
        for (int it = 0; it < 2; ++it)
#pragma unroll
            for (int jh = 0; jh < 2; ++jh) {
                const unsigned int w0a = bpermu(aA, c16[it][jh * 2][0]);
                const unsigned int w0b = bpermu(aA, c16[it][jh * 2 + 1][0]);
                const unsigned int w1a = bpermu(aA, c16[it][jh * 2][1]);
                const unsigned int w1b = bpermu(aA, c16[it][jh * 2 + 1][1]);
                const unsigned int w2a = bpermu(aB, c16[it][jh * 2][0]);
                const unsigned int w2b = bpermu(aB, c16[it][jh * 2 + 1][0]);
                const unsigned int w3a = bpermu(aB, c16[it][jh * 2][1]);
                const unsigned int w3b = bpermu(aB, c16[it][jh * 2 + 1][1]);
                u32x4 wv;
                wv[0] = hi ? w0b : w0a;
                wv[1] = hi ? w1b : w1a;
                wv[2] = hi ? w2b : w2a;
                wv[3] = hi ? w3b : w3a;
                pa[it][jh] = __builtin_bit_cast(f16x8, wv);
            }

        // ---- PV: D[i][c] += P[i][j] V[j][c] ----
#pragma unroll
        for (int it = 0; it < 2; ++it)
#pragma unroll
            for (int ct = 0; ct < 4; ++ct)
                oacc[it][ct] = __builtin_amdgcn_mfma_f32_16x16x32_f16(
                    pa[it][0], vf[0][ct], oacc[it][ct], 0, 0, 0);
#pragma unroll
        for (int it = 0; it < 2; ++it)
#pragma unroll
            for (int ct = 0; ct < 4; ++ct)
                oacc[it][ct] = __builtin_amdgcn_mfma_f32_16x16x32_f16(
                    pa[it][1], vf[1][ct], oacc[it][ct], 0, 0, 0);
    }

    // ---- epilogue: 4-way flash combine over jg ----
    if (cg == 0 && g4 == 0) {
#pragma unroll
        for (int it = 0; it < 2; ++it) {
            mfin[jg * 32 + it * 16 + m16] = mrow[it];
            lfin[jg * 32 + it * 16 + m16] = lrow[it];
        }
    }
    __syncthreads();

#pragma unroll
    for (int it = 0; it < 2; ++it)
#pragma unroll
        for (int r = 0; r < 4; ++r) {
            const int i = it * 16 + g4 * 4 + r;
            const float m0 = mfin[i], m1 = mfin[32 + i], m2 = mfin[64 + i], m3 = mfin[96 + i];
            const float M  = fmaxf(fmaxf(m0, m1), fmaxf(m2, m3));
            const float e0 = fexp2(m0 - M), e1 = fexp2(m1 - M),
                        e2 = fexp2(m2 - M), e3 = fexp2(m3 - M);
            const float den = lfin[i] * e0 + lfin[32 + i] * e1 +
                              lfin[64 + i] * e2 + lfin[96 + i] * e3;
            const float ej = (jg == 0) ? e0 : (jg == 1) ? e1 : (jg == 2) ? e2 : e3;
            const float wj = ej / den;
#pragma unroll
            for (int ct = 0; ct < 4; ++ct)
                Ocomb[jg][i][cg * 64 + ct * 16 + m16] = oacc[it][ct][r] * wj;
        }
    __syncthreads();

    const float gm = gamma[0];
    const int c  = tid >> 2;
    const int ib = (tid & 3) * 8;
#pragma unroll
    for (int h = 0; h < 2; ++h) {
        const int i = ib + h * 4;
        f32x4 o;
#pragma unroll
        for (int v = 0; v < 4; ++v)
            o[v] = Ocomb[0][i + v][c] + Ocomb[1][i + v][c] +
                   Ocomb[2][i + v][c] + Ocomb[3][i + v][c];
        const size_t idx = ((size_t)(b * CD + c)) * ND + i0 + i;
        const f32x4 xv = *reinterpret_cast<const f32x4*>(x + idx);
        f32x4 res;
#pragma unroll
        for (int v = 0; v < 4; ++v) res[v] = gm * o[v] + xv[v];
        *reinterpret_cast<f32x4*>(out + idx) = res;
    }
}

extern "C" void kernel_launch(void* const* d_in, const int* in_sizes, int n_in,
                              void* d_out, int out_size, void* d_ws, size_t ws_size,
                              hipStream_t stream) {
    const float* x     = (const float*)d_in[0];
    const float* wq    = (const float*)d_in[1];
    const float* bq    = (const float*)d_in[2];
    const float* wk    = (const float*)d_in[3];
    const float* bk    = (const float*)d_in[4];
    const float* bv    = (const float*)d_in[6];
    const float* wv    = (const float*)d_in[5];
    const float* gamma = (const float*)d_in[7];

    unsigned short* Qt = (unsigned short*)d_ws;               // 1MB (scaled by log2e)
    unsigned short* Kt = Qt + (size_t)NB * ND * CQ;           // 1MB
    unsigned short* Vp = Kt + (size_t)NB * ND * CQ;           // 8MB packed frags
    unsigned short* Wh = Vp + (size_t)NB * CD * ND;           // 160KB
    unsigned short* xh = Wh + (size_t)320 * CD;               // 8MB
    float* out = (float*)d_out;

    cvt_kernel<<<dim3(1104),      dim3(256),  0, stream>>>(x, wq, wk, wv, xh, Wh);
    proj_kernel<<<dim3(NB * 64),  dim3(320),  0, stream>>>(Wh, xh, bq, bk, bv, Qt, Kt, Vp);
    attn_kernel<<<dim3(NB * 128), dim3(1024), 0, stream>>>(Qt, Kt, Vp, x, gamma, out);
}

// Round 8
// 78.016 us; speedup vs baseline: 2.3510x; 2.2087x over previous
//
#include <hip/hip_runtime.h>
#include <stdint.h>

// SelfAttentionBlock: B=4, C=256, H=W=64 (N=4096), CQK=32.
//   cvt : W fp32->f16 (Wh) + x -> f16 transposed xh[b][n][c]
//   proj: register MFMA GEMM -> Qt[n][32]*log2e, Kt[n][32],
//         Vp = V pre-packed in PV B-fragment order [b][jblk][ct][lane][8]
//   attn: flash attention, 512 thr = 2 j-groups x 4 waves (round-3 topology).
//         V DIRECT from L2 via coalesced Vp fragments (no v_lds, no gl_lds,
//         no vmcnt drains). K global->reg prefetch. Swapped QK^T, lane-owns-row
//         softmax, defer-max, log2 domain. P double-buffered in LDS; ONE
//         lgkm-only barrier per 64-j step. 2-way flash combine in epilogue.

#define NB 4
#define CD 256
#define ND 4096
#define CQ 32
#define LOG2E 1.4426950408889634f

typedef __attribute__((ext_vector_type(4))) float f32x4;
typedef __attribute__((ext_vector_type(8))) _Float16 f16x8;
typedef __attribute__((ext_vector_type(4))) unsigned short u16x4;
typedef __attribute__((ext_vector_type(8))) unsigned short u16x8;
typedef __attribute__((ext_vector_type(2))) unsigned int u32x2;
typedef __attribute__((ext_vector_type(4))) int i32x4;

static __device__ __forceinline__ unsigned short f2h(float f) {
    union { _Float16 h; unsigned short u; } cv; cv.h = (_Float16)f; return cv.u;
}
static __device__ __forceinline__ float fexp2(float xv) {
    float r; asm("v_exp_f32 %0, %1" : "=v"(r) : "v"(xv)); return r;
}

#define BARRIER() asm volatile("s_waitcnt lgkmcnt(0)\n\ts_barrier" ::: "memory")

// ---------------- fused cvt: W fp32->f16 and x -> xh[b][n][c] f16 ----------------
__global__ __launch_bounds__(256) void cvt_kernel(
    const float* __restrict__ x,
    const float* __restrict__ wq, const float* __restrict__ wk,
    const float* __restrict__ wv,
    unsigned short* __restrict__ xh, unsigned short* __restrict__ Wh)
{
    __shared__ unsigned short xt[64 * 72];
    if (blockIdx.x >= 1024) {   // wcvt (80 blocks)
        const int idx = (blockIdx.x - 1024) * 256 + threadIdx.x;
        const int m = idx >> 6, kq = (idx & 63) << 2;
        const float* src = (m < 32) ? (wq + (size_t)m * CD + kq)
                         : (m < 64) ? (wk + (size_t)(m - 32) * CD + kq)
                                    : (wv + (size_t)(m - 64) * CD + kq);
        const f32x4 v = *reinterpret_cast<const f32x4*>(src);
        u16x4 h;
#pragma unroll
        for (int u = 0; u < 4; ++u) h[u] = f2h(v[u]);
        *reinterpret_cast<u16x4*>(Wh + (size_t)m * CD + kq) = h;
        return;
    }
    const int t  = threadIdx.x;
    const int nt = blockIdx.x & 63, ct = (blockIdx.x >> 6) & 3, b = blockIdx.x >> 8;
    const int n0 = nt << 6, c0 = ct << 6;

    const float* xb = x + ((size_t)(b * CD + c0)) * ND + n0;
#pragma unroll
    for (int s = t; s < 1024; s += 256) {
        const int c = s >> 4, nq = (s & 15) << 2;
        const f32x4 v = *reinterpret_cast<const f32x4*>(xb + (size_t)c * ND + nq);
        u16x4 h;
#pragma unroll
        for (int u = 0; u < 4; ++u) h[u] = f2h(v[u]);
        *reinterpret_cast<u16x4*>(&xt[c * 72 + nq]) = h;
    }
    __syncthreads();

    const int n = t >> 2, cb = (t & 3) << 4;
    u16x8 o0, o1;
#pragma unroll
    for (int u = 0; u < 8; ++u) o0[u] = xt[(cb + u) * 72 + n];
#pragma unroll
    for (int u = 0; u < 8; ++u) o1[u] = xt[(cb + 8 + u) * 72 + n];
    unsigned short* dst = xh + ((size_t)(b * ND + n0 + n)) * CD + c0 + cb;
    *reinterpret_cast<u16x8*>(dst)     = o0;
    *reinterpret_cast<u16x8*>(dst + 8) = o1;
}

// ---------------- projection: register MFMA GEMM ----------------
// wave 0: Q,K rows (D[c][n]); waves 1-4: V rows with swapped operands
// (D[n][c]) so each lane's 4 acc values are consecutive n -> one u16x4
// store into the Vp packed-fragment layout.
__global__ __launch_bounds__(320) void proj_kernel(
    const unsigned short* __restrict__ Wh, const unsigned short* __restrict__ xh,
    const float* __restrict__ bq, const float* __restrict__ bk,
    const float* __restrict__ bv,
    unsigned short* __restrict__ Qt, unsigned short* __restrict__ Kt,
    unsigned short* __restrict__ Vp)
{
    const int tid = threadIdx.x;
    const int lane = tid & 63;
    const int w = __builtin_amdgcn_readfirstlane(tid >> 6);
    const int m16 = lane & 15, g4 = lane >> 4;
    const int b = blockIdx.x >> 6, n0 = (blockIdx.x & 63) << 6;

    f32x4 acc[4][4];
#pragma unroll
    for (int a = 0; a < 4; ++a)
#pragma unroll
        for (int c = 0; c < 4; ++c) acc[a][c] = (f32x4){0.f, 0.f, 0.f, 0.f};

    const unsigned short* Wrow = Wh + (size_t)(w * 64 + m16) * CD;
    const unsigned short* Xrow = xh + ((size_t)(b * ND + n0 + m16)) * CD;

#pragma unroll
    for (int ks = 0; ks < 8; ++ks) {
        const int ko = ks * 32 + g4 * 8;
        f16x8 af[4], bf[4];
#pragma unroll
        for (int ms = 0; ms < 4; ++ms)
            af[ms] = *reinterpret_cast<const f16x8*>(Wrow + (size_t)ms * 16 * CD + ko);
#pragma unroll
        for (int ns = 0; ns < 4; ++ns)
            bf[ns] = *reinterpret_cast<const f16x8*>(Xrow + (size_t)ns * 16 * CD + ko);
        if (w == 0) {
#pragma unroll
            for (int ms = 0; ms < 4; ++ms)
#pragma unroll
                for (int ns = 0; ns < 4; ++ns)
                    acc[ms][ns] = __builtin_amdgcn_mfma_f32_16x16x32_f16(
                        af[ms], bf[ns], acc[ms][ns], 0, 0, 0);
        } else {
#pragma unroll
            for (int ms = 0; ms < 4; ++ms)
#pragma unroll
                for (int ns = 0; ns < 4; ++ns)
                    acc[ms][ns] = __builtin_amdgcn_mfma_f32_16x16x32_f16(
                        bf[ns], af[ms], acc[ms][ns], 0, 0, 0);
        }
    }

    if (w == 0) {   // Q (ms 0,1) + K (ms 2,3)
#pragma unroll
        for (int ms = 0; ms < 4; ++ms) {
            const int seg = ms * 16;
            const int mb  = seg + g4 * 4;
            const f32x4 bias = (seg < 32) ? *reinterpret_cast<const f32x4*>(bq + mb)
                                          : *reinterpret_cast<const f32x4*>(bk + (mb - 32));
#pragma unroll
            for (int ns = 0; ns < 4; ++ns) {
                const int n = n0 + ns * 16 + m16;
                u16x4 h;
                if (seg < 32) {
#pragma unroll
                    for (int r = 0; r < 4; ++r)
                        h[r] = f2h(fmaxf(acc[ms][ns][r] + bias[r], 0.f) * LOG2E);
                    *reinterpret_cast<u16x4*>(Qt + ((size_t)(b * ND + n)) * CQ + mb) = h;
                } else {
#pragma unroll
                    for (int r = 0; r < 4; ++r)
                        h[r] = f2h(fmaxf(acc[ms][ns][r] + bias[r], 0.f));
                    *reinterpret_cast<u16x4*>(Kt + ((size_t)(b * ND + n)) * CQ + (mb - 32)) = h;
                }
            }
        }
    } else {        // V: D[n][c], rows n = g4*4+r, cols c = m16
        const int cbase = (w - 1) * 64;
#pragma unroll
        for (int ms = 0; ms < 4; ++ms) {
            const int c = cbase + ms * 16 + m16;
            const float bval = bv[c];
#pragma unroll
            for (int ns = 0; ns < 4; ++ns) {
                const int n = n0 + ns * 16 + g4 * 4;
                u16x4 h;
#pragma unroll
                for (int r = 0; r < 4; ++r)
                    h[r] = f2h(fmaxf(acc[ms][ns][r] + bval, 0.f));
                unsigned short* dst = Vp
                    + ((size_t)((b * 128 + (n >> 5)) * 16 + (c >> 4))) * 512
                    + ((((n >> 3) & 3) * 16 + (c & 15)) * 8) + (n & 7);
                *reinterpret_cast<u16x4*>(dst) = h;
            }
        }
    }
}

// ---------------- flash attention: r3 topology + Vp-direct + slim LDS ----------------
// grid: NB*64 blocks (b, 64-row i-strip), 512 threads (8 waves, 2 j-groups x 4).
// Group g owns j in [g*2048, g*2048+2048), 32 steps of 64 j. Per step per wave:
// QK^T (swapped) on 16-i strip -> softmax -> P->LDS -> BARRIER -> rescale -> PV
// on 64-c slice with V frags direct from global/L2. One barrier per step.
__global__ __launch_bounds__(512, 2) void attn_kernel(
    const unsigned short* __restrict__ Qt, const unsigned short* __restrict__ Kt,
    const unsigned short* __restrict__ Vp, const float* __restrict__ x,
    const float* __restrict__ gamma, float* __restrict__ out)
{
    // 0..32767      p_lds   [2 groups][2 buf][64 i][128 B]  (f16, XOR-swizzled)
    // 32768..34815  scales  [2][2][64] f32
    // 34816..34879  flags   [2][2][4]  i32
    // epilogue: Ocomb [64][260] f32 @0 (aliases loop LDS); mfin/lfin/wfac above
    __shared__ __align__(16) unsigned char smem[68096];
    float* scales = reinterpret_cast<float*>(smem + 32768);
    int*   flags  = reinterpret_cast<int*>(smem + 34816);
    float* Ocomb  = reinterpret_cast<float*>(smem);
    float* mfin   = reinterpret_cast<float*>(smem + 66560);  // [2][64]
    float* lfin   = reinterpret_cast<float*>(smem + 67072);  // [2][64]
    float* wfac   = reinterpret_cast<float*>(smem + 67584);  // [2][64]

    const int tid  = threadIdx.x;
    const int lane = tid & 63;
    const int w8   = __builtin_amdgcn_readfirstlane(tid >> 6);
    const int g    = w8 >> 2;       // j-group
    const int ws   = w8 & 3;        // i-strip (QK) / c-slice (PV)
    const int m16  = lane & 15;
    const int g4   = lane >> 4;
    const int wg   = (blockIdx.x & 7) * 32 + (blockIdx.x >> 3);  // XCD swizzle
    const int b    = wg >> 6;
    const int i0   = (wg & 63) << 6;

    // Q as B-operand: col=i=ws*16+m16, k=g4*8+u
    const f16x8 qfrag = *reinterpret_cast<const f16x8*>(
        Qt + ((size_t)(b * ND + i0 + ws * 16 + m16)) * CQ + g4 * 8);
    // K as A-operand from global: row j=m16 (+16*jt), k=g4*8+u  (1KB/wave, coalesced)
    const unsigned short* kb = Kt + ((size_t)(b * ND + m16)) * CQ + g4 * 8;
    // V B-frags, packed layout: 16B/lane, 1KB/wave contiguous per frag
    const unsigned short* vpc =
        Vp + ((size_t)(b * 128 * 16 + ws * 4)) * 512 + lane * 8;

    f32x4 oacc[4][4];
#pragma unroll
    for (int a = 0; a < 4; ++a)
#pragma unroll
        for (int c = 0; c < 4; ++c) oacc[a][c] = (f32x4){0.f, 0.f, 0.f, 0.f};
    float mrow = -1e30f, lrow = 0.f;
    const f32x4 zero4 = {0.f, 0.f, 0.f, 0.f};

    const int jbase = g * 2048;
    const int irow  = ws * 16 + m16;
    const int iswz  = (m16 & 7) << 4;     // == (irow&7)<<4

    auto LOADK = [&](f16x8 (&kr)[4], int j) {
#pragma unroll
        for (int t = 0; t < 4; ++t)
            kr[t] = *reinterpret_cast<const f16x8*>(kb + (size_t)(j + t * 16) * CQ);
    };

    auto STEP = [&](int k, f16x8 (&kc)[4], f16x8 (&kn)[4]) {
        const int j0  = jbase + k * 64;
        const int par = k & 1;
        unsigned char* pb = smem + g * 16384 + par * 8192;

        // issue V frag loads now; consumed after the barrier (latency hidden)
        const int jblk0 = j0 >> 5;
        f16x8 vf[2][4];
#pragma unroll
        for (int jh = 0; jh < 2; ++jh)
#pragma unroll
            for (int cs = 0; cs < 4; ++cs)
                vf[jh][cs] = *reinterpret_cast<const f16x8*>(
                    vpc + (size_t)((jblk0 + jh) * 16 + cs) * 512);
        // prefetch next step's K
        const int jn = (k < 31) ? (j0 + 64) : jbase;
        LOADK(kn, jn);

        // ---- QK^T swapped: D[j][i], col=i=irow, lane holds 16 j values ----
        f32x4 s[4];
#pragma unroll
        for (int t = 0; t < 4; ++t)
            s[t] = __builtin_amdgcn_mfma_f32_16x16x32_f16(kc[t], qfrag, zero4, 0, 0, 0);

        // ---- softmax (log2 domain, defer-max) ----
        float pm = s[0][0];
#pragma unroll
        for (int t = 0; t < 4; ++t)
#pragma unroll
            for (int r = 0; r < 4; ++r) pm = fmaxf(pm, s[t][r]);
        pm = fmaxf(pm, __shfl_xor(pm, 16));
        pm = fmaxf(pm, __shfl_xor(pm, 32));
        float sc = 1.0f;
        int myresc = 0;
        if (__ballot(pm <= mrow + 8.0f) != ~0ull) {
            const float mnew = fmaxf(mrow, pm);
            sc = fexp2(mrow - mnew);
            mrow = mnew;
            myresc = 1;
        }
        float rs = 0.f;
#pragma unroll
        for (int t = 0; t < 4; ++t)
#pragma unroll
            for (int r = 0; r < 4; ++r) { s[t][r] = fexp2(s[t][r] - mrow); rs += s[t][r]; }
        rs += __shfl_xor(rs, 16);
        rs += __shfl_xor(rs, 32);
        lrow = lrow * sc + rs;

        // ---- P -> LDS (4x ds_write_b64, swizzled) + scale + flag ----
#pragma unroll
        for (int t = 0; t < 4; ++t) {
            u32x2 pw;
            pw[0] = __builtin_bit_cast(unsigned int,
                        __builtin_amdgcn_cvt_pkrtz(s[t][0], s[t][1]));
            pw[1] = __builtin_bit_cast(unsigned int,
                        __builtin_amdgcn_cvt_pkrtz(s[t][2], s[t][3]));
            const int lo = (irow * 128 + t * 32 + g4 * 8) ^ iswz;
            *reinterpret_cast<u32x2*>(pb + lo) = pw;
        }
        if (g4 == 0)   scales[(g * 2 + par) * 64 + irow] = sc;
        if (lane == 0) flags[(g * 2 + par) * 4 + ws] = myresc;

        BARRIER();   // lgkm-only: P/scale/flag visible; V loads stay in flight

        // ---- rescale oacc if any row of the group rescaled ----
        const i32x4 fl = *reinterpret_cast<const i32x4*>(flags + (g * 2 + par) * 4);
        const int anyresc = __builtin_amdgcn_readfirstlane(fl[0] | fl[1] | fl[2] | fl[3]);
        if (anyresc) {
#pragma unroll
            for (int is = 0; is < 4; ++is) {
                const f32x4 sr = *reinterpret_cast<const f32x4*>(
                    scales + (g * 2 + par) * 64 + is * 16 + g4 * 4);
#pragma unroll
                for (int r = 0; r < 4; ++r)
#pragma unroll
                    for (int cs = 0; cs < 4; ++cs) oacc[is][cs][r] *= sr[r];
            }
        }

        // ---- PV: P A-frags from LDS, V B-frags from registers (global) ----
        __builtin_amdgcn_s_setprio(1);
#pragma unroll
        for (int jh = 0; jh < 2; ++jh) {
#pragma unroll
            for (int is = 0; is < 4; ++is) {
                const int lo = ((is * 16 + m16) * 128 + jh * 64 + g4 * 16) ^ iswz;
                const f16x8 pf = *reinterpret_cast<const f16x8*>(pb + lo);
#pragma unroll
                for (int cs = 0; cs < 4; ++cs)
                    oacc[is][cs] = __builtin_amdgcn_mfma_f32_16x16x32_f16(
                        pf, vf[jh][cs], oacc[is][cs], 0, 0, 0);
            }
        }
        __builtin_amdgcn_s_setprio(0);
    };

    f16x8 kA[4], kB[4];
    LOADK(kA, jbase);

#pragma unroll 1
    for (int k2 = 0; k2 < 16; ++k2) {
        STEP(2 * k2,     kA, kB);
        STEP(2 * k2 + 1, kB, kA);
    }

    // ---- epilogue: 2-way flash combine over j-groups ----
    if (g4 == 0) { mfin[g * 64 + irow] = mrow; lfin[g * 64 + irow] = lrow; }
    __syncthreads();

    if (tid < 128) {
        const int gg = tid >> 6, i = tid & 63;
        const float m0 = mfin[i], m1 = mfin[64 + i];
        const float M  = fmaxf(m0, m1);
        const float e0 = fexp2(m0 - M), e1 = fexp2(m1 - M);
        const float den = lfin[i] * e0 + lfin[64 + i] * e1;
        wfac[tid] = ((gg == 0) ? e0 : e1) / den;
    }
    __syncthreads();   // loop LDS dead; Ocomb aliases it from here

    if (g == 0) {
#pragma unroll
        for (int is = 0; is < 4; ++is) {
            const f32x4 f = *reinterpret_cast<const f32x4*>(wfac + is * 16 + g4 * 4);
#pragma unroll
            for (int cs = 0; cs < 4; ++cs)
#pragma unroll
                for (int r = 0; r < 4; ++r)
                    Ocomb[(is * 16 + g4 * 4 + r) * 260 + ws * 64 + cs * 16 + m16] =
                        oacc[is][cs][r] * f[r];
        }
    }
    __syncthreads();
    if (g == 1) {
#pragma unroll
        for (int is = 0; is < 4; ++is) {
            const f32x4 f = *reinterpret_cast<const f32x4*>(wfac + 64 + is * 16 + g4 * 4);
#pragma unroll
            for (int cs = 0; cs < 4; ++cs)
#pragma unroll
                for (int r = 0; r < 4; ++r)
                    Ocomb[(is * 16 + g4 * 4 + r) * 260 + ws * 64 + cs * 16 + m16] +=
                        oacc[is][cs][r] * f[r];
        }
    }
    __syncthreads();

    const float gm = gamma[0];
#pragma unroll
    for (int pass = 0; pass < 8; ++pass) {
        const int c  = (tid >> 4) + pass * 32;
        const int ib = (tid & 15) * 4;
        f32x4 o;
#pragma unroll
        for (int u = 0; u < 4; ++u) o[u] = Ocomb[(ib + u) * 260 + c];
        const size_t idx = ((size_t)(b * CD + c)) * ND + i0 + ib;
        const f32x4 xv = *reinterpret_cast<const f32x4*>(x + idx);
        f32x4 res;
#pragma unroll
        for (int u = 0; u < 4; ++u) res[u] = gm * o[u] + xv[u];
        *reinterpret_cast<f32x4*>(out + idx) = res;
    }
}

extern "C" void kernel_launch(void* const* d_in, const int* in_sizes, int n_in,
                              void* d_out, int out_size, void* d_ws, size_t ws_size,
                              hipStream_t stream) {
    const float* x     = (const float*)d_in[0];
    const float* wq    = (const float*)d_in[1];
    const float* bq    = (const float*)d_in[2];
    const float* wk    = (const float*)d_in[3];
    const float* bk    = (const float*)d_in[4];
    const float* wv    = (const float*)d_in[5];
    const float* bv    = (const float*)d_in[6];
    const float* gamma = (const float*)d_in[7];

    unsigned short* Qt = (unsigned short*)d_ws;               // 1MB (scaled by log2e)
    unsigned short* Kt = Qt + (size_t)NB * ND * CQ;           // 1MB
    unsigned short* Vp = Kt + (size_t)NB * ND * CQ;           // 8MB packed frags
    unsigned short* Wh = Vp + (size_t)NB * CD * ND;           // 160KB
    unsigned short* xh = Wh + (size_t)320 * CD;               // 8MB
    float* out = (float*)d_out;

    cvt_kernel<<<dim3(1104),     dim3(256), 0, stream>>>(x, wq, wk, wv, xh, Wh);
    proj_kernel<<<dim3(NB * 64), dim3(320), 0, stream>>>(Wh, xh, bq, bk, bv, Qt, Kt, Vp);
    attn_kernel<<<dim3(NB * 64), dim3(512), 0, stream>>>(Qt, Kt, Vp, x, gamma, out);
}